// Round 1
// baseline (48.819 us; speedup 1.0000x reference)
//
#include <hip/hip_runtime.h>
#include <hip/hip_bf16.h>

// Problem constants (fixed by the reference file)
constexpr int B_ = 8;
constexpr int C_ = 3;
constexpr int HW_ = 1024 * 1024;          // H*W
constexpr int NPIX = B_ * HW_;            // 8,388,608 pixels
constexpr int NV   = NPIX / 4;            // float4 groups over pixel space
constexpr int HWV  = HW_ / 4;             // 262144 = 2^18 vec groups per image
// ln(1e-8)
#define LOGMIN (-18.420680743952367f)
// 1/(B*H*W) = 2^-23 (exact in fp32)
#define INV_DENOM (1.1920928955078125e-07f)

__global__ void zero_out_kernel(float* out) {
    if (threadIdx.x == 0) out[0] = 0.0f;
}

__global__ __launch_bounds__(256) void ce_fused_kernel(
    const float* __restrict__ x,        // [B][C][H][W]
    const int*   __restrict__ y,        // [B][H][W]
    const float* __restrict__ weight,   // [C]
    const float* __restrict__ mask,     // [B][H][W]
    float* __restrict__ out)
{
    const float w0 = weight[0];
    const float w1 = weight[1];
    const float w2 = weight[2];

    float acc = 0.0f;   // accumulates w[y] * logp_y * mask  (positive-sign form)

    const int tid    = blockIdx.x * blockDim.x + threadIdx.x;
    const int stride = gridDim.x * blockDim.x;

    for (int pv = tid; pv < NV; pv += stride) {
        const int b  = pv >> 18;            // pv / HWV
        const int sv = pv & (HWV - 1);      // pv % HWV
        const size_t base = (size_t)b * (size_t)(C_ * HW_) + (size_t)sv * 4;

        const float4 xa = *reinterpret_cast<const float4*>(x + base);
        const float4 xb = *reinterpret_cast<const float4*>(x + base + HW_);
        const float4 xc = *reinterpret_cast<const float4*>(x + base + 2 * (size_t)HW_);
        const int4   yv = *reinterpret_cast<const int4*>(y + (size_t)pv * 4);
        const float4 mv = *reinterpret_cast<const float4*>(mask + (size_t)pv * 4);

        const float a0[4] = {xa.x, xa.y, xa.z, xa.w};
        const float a1[4] = {xb.x, xb.y, xb.z, xb.w};
        const float a2[4] = {xc.x, xc.y, xc.z, xc.w};
        const int   yy[4] = {yv.x, yv.y, yv.z, yv.w};
        const float mm[4] = {mv.x, mv.y, mv.z, mv.w};

        #pragma unroll
        for (int j = 0; j < 4; ++j) {
            const float v0 = a0[j], v1 = a1[j], v2 = a2[j];
            const float m = fmaxf(fmaxf(v0, v1), v2);
            const float t = __expf(v0 - m) + __expf(v1 - m) + __expf(v2 - m);
            const float lse = m + __logf(t);
            const int   c  = yy[j];
            const float ay = (c == 0) ? v0 : ((c == 1) ? v1 : v2);
            const float wy = (c == 0) ? w0 : ((c == 1) ? w1 : w2);
            const float lp = fmaxf(ay - lse, LOGMIN);
            acc = fmaf(wy * lp, mm[j], acc);
        }
    }

    // wave (64-lane) reduction
    #pragma unroll
    for (int off = 32; off > 0; off >>= 1)
        acc += __shfl_down(acc, off, 64);

    __shared__ float wsum[4];   // 256 threads / 64 lanes
    const int lane = threadIdx.x & 63;
    const int wid  = threadIdx.x >> 6;
    if (lane == 0) wsum[wid] = acc;
    __syncthreads();

    if (threadIdx.x == 0) {
        const float s = wsum[0] + wsum[1] + wsum[2] + wsum[3];
        atomicAdd(out, s * (-INV_DENOM));   // ce = -w*lp*mask, then / denom
    }
}

extern "C" void kernel_launch(void* const* d_in, const int* in_sizes, int n_in,
                              void* d_out, int out_size, void* d_ws, size_t ws_size,
                              hipStream_t stream) {
    const float* x      = (const float*)d_in[0];
    const int*   y      = (const int*)d_in[1];
    const float* weight = (const float*)d_in[2];
    const float* mask   = (const float*)d_in[3];
    float* out = (float*)d_out;

    zero_out_kernel<<<1, 64, 0, stream>>>(out);

    const int block = 256;
    const int grid  = 2048;   // 256 CUs * 8 blocks/CU; grid-stride covers NV
    ce_fused_kernel<<<grid, block, 0, stream>>>(x, y, weight, mask, out);
}